// Round 15
// baseline (938.018 us; speedup 1.0000x reference)
//
#include <hip/hip_runtime.h>
#include <math.h>

// TransformerBlock1: b=4, DIM=192, h=256, w=192, HEADS=8, HID=768
#define SSP   49152
#define HDIM  256
#define WDIM  192
#define CDIM  192
#define NHEAD 8
#define CH    24
#define OC3   576
#define HIDF  768
#define NB    4
#define SCCH  24

typedef short bf16x8 __attribute__((ext_vector_type(8)));
typedef short bf16x4 __attribute__((ext_vector_type(4)));
typedef float f32x4  __attribute__((ext_vector_type(4)));

__device__ inline short f2bf(float f) {
  unsigned u = __float_as_uint(f);
  u += 0x7fffu + ((u >> 16) & 1u);
  return (short)(u >> 16);
}
__device__ inline float bf2f(short h) {
  return __uint_as_float(((unsigned)(unsigned short)h) << 16);
}

// async global->LDS 16B: dest is wave-uniform base + lane*16
__device__ inline void gl_lds16(const short* g, short* l) {
  __builtin_amdgcn_global_load_lds(
      (const __attribute__((address_space(1))) unsigned int*)g,
      (__attribute__((address_space(3))) unsigned int*)l, 16, 0, 0);
}

// ---------------- all four weights -> bf16, one launch ----------------
__global__ __launch_bounds__(256) void cvt_all(const float* __restrict__ s0,
                                               const float* __restrict__ s1,
                                               const float* __restrict__ s2,
                                               const float* __restrict__ s3,
                                               short* __restrict__ dst) {
  int i = blockIdx.x * 256 + threadIdx.x;   // < 442368
  float v;
  if (i < 110592)      v = s0[i];
  else if (i < 147456) v = s1[i - 110592];
  else if (i < 294912) v = s2[i - 147456];
  else                 v = s3[i - 294912];
  dst[i] = f2bf(v);
}

// ---------------- LN1: fp32 x -> y1t bf16 [s][192] + raw xw bf16 [c][s] ----------------
__global__ __launch_bounds__(256) void ln1_bf16(const float* __restrict__ x,
                                                const float* __restrict__ w,
                                                const float* __restrict__ bia,
                                                short* __restrict__ yt,
                                                short* __restrict__ xw) {
  __shared__ float xs[192][68];
  __shared__ float ps[4][64], pq[4][64], mus[64], rst[64];
  const int tid = threadIdx.x;
  const int s0 = blockIdx.x * 64;
  const float* xb = x + (size_t)blockIdx.y * CDIM * SSP;
  short* ytb = yt + (size_t)blockIdx.y * SSP * CDIM;
  short* xwb = xw + (size_t)blockIdx.y * CDIM * SSP;
#pragma unroll
  for (int it = 0; it < 12; ++it) {
    int u = it * 256 + tid;
    int c = u >> 4, q = u & 15;
    float4 v = *(const float4*)(xb + (size_t)c * SSP + s0 + q * 4);
    *(float4*)&xs[c][q * 4] = v;
  }
  __syncthreads();
  {
    int s = tid & 63, p = tid >> 6;
    float sm = 0.f, sq = 0.f;
    for (int c = p * 48; c < p * 48 + 48; ++c) {
      float v = xs[c][s]; sm += v; sq += v * v;
    }
    ps[p][s] = sm; pq[p][s] = sq;
  }
  __syncthreads();
  if (tid < 64) {
    float sm = ps[0][tid] + ps[1][tid] + ps[2][tid] + ps[3][tid];
    float sq = pq[0][tid] + pq[1][tid] + pq[2][tid] + pq[3][tid];
    float mu = sm * (1.f / CDIM);
    mus[tid] = mu;
    rst[tid] = rsqrtf(sq * (1.f / CDIM) - mu * mu + 1e-5f);
  }
  __syncthreads();
  // y1t transposed write
#pragma unroll
  for (int it = 0; it < 6; ++it) {
    int u = it * 256 + tid;
    int c8 = u >> 6, sr = u & 63;
    float mu = mus[sr], r = rst[sr];
    bf16x8 o;
#pragma unroll
    for (int j = 0; j < 8; ++j) {
      int c = c8 * 8 + j;
      o[j] = f2bf((xs[c][sr] - mu) * r * w[c] + bia[c]);
    }
    *(bf16x8*)(ytb + (size_t)(s0 + sr) * CDIM + c8 * 8) = o;
  }
  // raw x copy, natural [c][s]
#pragma unroll
  for (int it = 0; it < 6; ++it) {
    int u = it * 256 + tid;
    int c = u >> 3, sv = u & 7;
    bf16x8 o;
#pragma unroll
    for (int j = 0; j < 8; ++j) o[j] = f2bf(xs[c][sv * 8 + j]);
    *(bf16x8*)(xwb + (size_t)c * SSP + s0 + sv * 8) = o;
  }
}

// ---------------- MFMA bf16 GEMM NT (64x256), gl_lds staging, BK=64 ----------------
template <bool RESID, bool OUT_BF16>
__global__ __launch_bounds__(256) void mfma_gemmx(
    const short* __restrict__ A, const short* __restrict__ B,
    const float* __restrict__ resid, void* __restrict__ Cv,
    int M, int N, int K, long long strideB, long long strideC) {
  __shared__ short As[2][64 * 32];
  __shared__ short Bs[2][256 * 32];
  const int tid = threadIdx.x;
  const int m0 = blockIdx.y * 64, n0 = blockIdx.x * 256;
  const long long z = blockIdx.z;
  const short* Bz = B + z * strideB;
  const int w = tid >> 6, lane = tid & 63;
  const int r16 = lane & 15, kg = lane >> 4;
  const int arow = tid >> 2, ac4 = tid & 3;

  f32x4 acc[4][4] = {};

  for (int k0 = 0; k0 < K; k0 += 64) {
#pragma unroll
    for (int s = 0; s < 2; ++s) {
      gl_lds16(A + (size_t)(m0 + arow) * K + k0 + s * 32 + ac4 * 8, As[s] + w * 512);
#pragma unroll
      for (int p = 0; p < 4; ++p) {
        int flat = p * 256 + tid;
        int brow = flat >> 2, bc4 = flat & 3;
        gl_lds16(Bz + (size_t)(n0 + brow) * K + k0 + s * 32 + bc4 * 8, Bs[s] + p * 2048 + w * 512);
      }
    }
    __syncthreads();
#pragma unroll
    for (int s = 0; s < 2; ++s) {
      bf16x8 af[4], bfr[4];
#pragma unroll
      for (int i = 0; i < 4; ++i)
        af[i] = *(bf16x8*)(&As[s][(i * 16 + r16) * 32 + kg * 8]);
#pragma unroll
      for (int j = 0; j < 4; ++j)
        bfr[j] = *(bf16x8*)(&Bs[s][(w * 64 + j * 16 + r16) * 32 + kg * 8]);
#pragma unroll
      for (int i = 0; i < 4; ++i)
#pragma unroll
        for (int j = 0; j < 4; ++j)
          acc[i][j] = __builtin_amdgcn_mfma_f32_16x16x32_bf16(af[i], bfr[j], acc[i][j], 0, 0, 0);
    }
    __syncthreads();
  }

  float* Cf = (float*)Cv + z * strideC;
  short* Ch = (short*)Cv + z * strideC;
  const float* R = RESID ? resid + z * strideC : nullptr;
#pragma unroll
  for (int i = 0; i < 4; ++i) {
#pragma unroll
    for (int j = 0; j < 4; ++j) {
#pragma unroll
      for (int t = 0; t < 4; ++t) {
        int m = m0 + i * 16 + kg * 4 + t;
        int n = n0 + w * 64 + j * 16 + r16;
        float v = acc[i][j][t];
        size_t idx = (size_t)m * N + n;
        if (RESID) v += R[idx];
        if (OUT_BF16) Ch[idx] = f2bf(v); else Cf[idx] = v;
      }
    }
  }
}

// ---------------- proj + LN2 fused: BM=192 (all channels) x BN=64 spatial ----------------
// x1 = wp @ pvt + xw(bf16); writes x1w bf16 [c][s]; LN over channels -> y2 bf16 [c][s].
__global__ __launch_bounds__(256) void proj_ln2(const short* __restrict__ wp,
                                                const short* __restrict__ pvt,
                                                const short* __restrict__ xw,
                                                const float* __restrict__ lw,
                                                const float* __restrict__ lb,
                                                short* __restrict__ x1w,
                                                short* __restrict__ y2) {
  __shared__ short As[2][192 * 32];   // 24 KB
  __shared__ short Bs[2][64 * 32];    // 8 KB
  __shared__ float lnp[2][16][64];    // 8 KB
  __shared__ float mus[64], rst[64];
  const int tid = threadIdx.x;
  const int n0 = blockIdx.x * 64;
  const size_t zN = (size_t)blockIdx.y * CDIM * SSP;
  const short* Bz = pvt + (size_t)blockIdx.y * SSP * CDIM;
  const int w = tid >> 6, lane = tid & 63;
  const int r16 = lane & 15, kg = lane >> 4;

  f32x4 acc[3][4] = {};

  for (int k0 = 0; k0 < 192; k0 += 64) {
#pragma unroll
    for (int s = 0; s < 2; ++s) {
      // A: 192 rows x 32 shorts = 768 chunks (3 full passes)
#pragma unroll
      for (int p = 0; p < 3; ++p) {
        int flat = p * 256 + tid;
        int row = flat >> 2, c4 = flat & 3;
        gl_lds16(wp + (size_t)row * CDIM + k0 + s * 32 + c4 * 8,
                 As[s] + p * 2048 + w * 512);
      }
      // B: 64 rows x 32 shorts = 256 chunks
      {
        int row = tid >> 2, c4 = tid & 3;
        gl_lds16(Bz + (size_t)(n0 + row) * CDIM + k0 + s * 32 + c4 * 8,
                 Bs[s] + w * 512);
      }
    }
    __syncthreads();
#pragma unroll
    for (int s = 0; s < 2; ++s) {
      bf16x8 af[3], bfr[4];
#pragma unroll
      for (int i = 0; i < 3; ++i)
        af[i] = *(bf16x8*)(&As[s][(w * 48 + i * 16 + r16) * 32 + kg * 8]);
#pragma unroll
      for (int j = 0; j < 4; ++j)
        bfr[j] = *(bf16x8*)(&Bs[s][(j * 16 + r16) * 32 + kg * 8]);
#pragma unroll
      for (int i = 0; i < 3; ++i)
#pragma unroll
        for (int j = 0; j < 4; ++j)
          acc[i][j] = __builtin_amdgcn_mfma_f32_16x16x32_bf16(af[i], bfr[j], acc[i][j], 0, 0, 0);
    }
    __syncthreads();
  }

  // epilogue: x1 = acc + xw; write x1w; accumulate LN partials
  float psum[4] = {}, psq[4] = {};
#pragma unroll
  for (int i = 0; i < 3; ++i)
#pragma unroll
    for (int j = 0; j < 4; ++j)
#pragma unroll
      for (int t = 0; t < 4; ++t) {
        int c = w * 48 + i * 16 + kg * 4 + t;
        int s = n0 + j * 16 + r16;
        size_t idx = zN + (size_t)c * SSP + s;
        float v = acc[i][j][t] + bf2f(xw[idx]);
        x1w[idx] = f2bf(v);
        acc[i][j][t] = v;
        psum[j] += v; psq[j] += v * v;
      }
#pragma unroll
  for (int j = 0; j < 4; ++j) {
    lnp[0][w * 4 + kg][j * 16 + r16] = psum[j];
    lnp[1][w * 4 + kg][j * 16 + r16] = psq[j];
  }
  __syncthreads();
  if (tid < 64) {
    float sm = 0.f, sq = 0.f;
#pragma unroll
    for (int p = 0; p < 16; ++p) { sm += lnp[0][p][tid]; sq += lnp[1][p][tid]; }
    float mu = sm * (1.f / CDIM);
    mus[tid] = mu;
    rst[tid] = rsqrtf(sq * (1.f / CDIM) - mu * mu + 1e-5f);
  }
  __syncthreads();
#pragma unroll
  for (int i = 0; i < 3; ++i)
#pragma unroll
    for (int j = 0; j < 4; ++j) {
      int sl = j * 16 + r16;
      float mu = mus[sl], r = rst[sl];
#pragma unroll
      for (int t = 0; t < 4; ++t) {
        int c = w * 48 + i * 16 + kg * 4 + t;
        size_t idx = zN + (size_t)c * SSP + n0 + sl;
        y2[idx] = f2bf((acc[i][j][t] - mu) * r * lw[c] + lb[c]);
      }
    }
}

// ---------------- 3x3 depthwise conv, LDS-tiled, bf16->bf16, batched ----------------
__global__ __launch_bounds__(256) void dwconv_tile(const short* __restrict__ in,
                                                   const float* __restrict__ w9,
                                                   short* __restrict__ out) {
  __shared__ short tile[34][208];
  const int tid = threadIdx.x;
  const int ch = blockIdx.x >> 3;        // b*OC3 + o
  const int slab = blockIdx.x & 7;
  const int o = ch % OC3;
  const int y0 = slab * 32;
  float wr[9];
#pragma unroll
  for (int i = 0; i < 9; ++i) wr[i] = w9[o * 9 + i];
  const short* ip = in + (size_t)ch * SSP;

  if (tid < 34) { tile[tid][7] = 0; tile[tid][200] = 0; }
#pragma unroll
  for (int i = 0; i < 4; ++i) {
    int idx = i * 256 + tid;
    if (idx < 816) {
      int row = idx / 24, cx = idx - row * 24;
      int gy = y0 + row - 1;
      bf16x8 v = {};
      if (gy >= 0 && gy < HDIM) v = *(const bf16x8*)(ip + gy * WDIM + cx * 8);
      *(bf16x8*)(&tile[row][8 + cx * 8]) = v;
    }
  }
  __syncthreads();

  short* op = out + (size_t)ch * SSP;
#pragma unroll
  for (int g = 0; g < 3; ++g) {
    int G = g * 256 + tid;
    int r = G / 24, cx = G - (G / 24) * 24;
    int cb = cx * 8 + 7;
    float a[10], b[10], c[10];
#pragma unroll
    for (int d = 0; d < 10; ++d) {
      a[d] = bf2f(tile[r][cb + d]);
      b[d] = bf2f(tile[r + 1][cb + d]);
      c[d] = bf2f(tile[r + 2][cb + d]);
    }
    bf16x8 ov;
#pragma unroll
    for (int j = 0; j < 8; ++j) {
      float acc = wr[0] * a[j] + wr[1] * a[j + 1] + wr[2] * a[j + 2]
                + wr[3] * b[j] + wr[4] * b[j + 1] + wr[5] * b[j + 2]
                + wr[6] * c[j] + wr[7] * c[j + 1] + wr[8] * c[j + 2];
      ov[j] = f2bf(acc);
    }
    *(bf16x8*)(op + (y0 + r) * WDIM + cx * 8) = ov;
  }
}

// ---------------- scores stage1: partial dots + per-row sumsq chunks (batched z) ----------------
__global__ __launch_bounds__(256) void scores_stage1(const short* __restrict__ D,
                                                     float* __restrict__ pdot,
                                                     float* __restrict__ qss,
                                                     float* __restrict__ kss) {
  int ch = blockIdx.x, h = blockIdx.y, b = blockIdx.z;
  __shared__ float qs[24][260];
  __shared__ float ks[24][260];
  int tid = threadIdx.x;
  int w = tid >> 6, lane = tid & 63;
  int c0 = w * 6;
  float acc[6] = {0.f, 0.f, 0.f, 0.f, 0.f, 0.f};
  float ssacc = 0.f;
  const short* qb = D + ((size_t)b * OC3 + h * CH) * SSP;
  const short* kb = D + ((size_t)b * OC3 + CDIM + h * CH) * SSP;
  for (int it = 0; it < 8; ++it) {
    int s0 = ch * 2048 + it * 256;
#pragma unroll
    for (int p = 0; p < 3; ++p) {
      int u = p * 256 + tid;
      int row = u >> 5, col8 = u & 31;
      bf16x8 qv = *(const bf16x8*)(qb + (size_t)row * SSP + s0 + col8 * 8);
      bf16x8 kv = *(const bf16x8*)(kb + (size_t)row * SSP + s0 + col8 * 8);
#pragma unroll
      for (int j = 0; j < 8; ++j) {
        qs[row][col8 * 8 + j] = bf2f(qv[j]);
        ks[row][col8 * 8 + j] = bf2f(kv[j]);
      }
    }
    __syncthreads();
    if (w < 2 && lane < 24) {
      const float (*src)[260] = (w == 0) ? qs : ks;
      for (int s = 0; s < 256; s += 4) {
        float4 v = *(const float4*)&src[lane][s];
        ssacc += v.x * v.x + v.y * v.y + v.z * v.z + v.w * v.w;
      }
    }
    if (lane < 24) {
      for (int s = 0; s < 256; s += 4) {
        float4 kv = *(float4*)&ks[lane][s];
#pragma unroll
        for (int i = 0; i < 6; ++i) {
          float4 qv = *(float4*)&qs[c0 + i][s];
          acc[i] += qv.x * kv.x + qv.y * kv.y + qv.z * kv.z + qv.w * kv.w;
        }
      }
    }
    __syncthreads();
  }
  if (lane < 24) {
    float* pb = pdot + (size_t)b * (NHEAD * CH * CH * SCCH);
#pragma unroll
    for (int i = 0; i < 6; ++i)
      pb[(((size_t)h * CH + (c0 + i)) * CH + lane) * SCCH + ch] = acc[i];
    if (w == 0) qss[(((size_t)b * NHEAD + h) * CH + lane) * SCCH + ch] = ssacc;
    if (w == 1) kss[(((size_t)b * NHEAD + h) * CH + lane) * SCCH + ch] = ssacc;
  }
}

// ---------------- scores reduce + norms + temperature + softmax (batched z) ----------------
__global__ void scores_reduce(const float* __restrict__ pdot,
                              const float* __restrict__ qss,
                              const float* __restrict__ kss,
                              const float* __restrict__ temp,
                              float* __restrict__ atn) {
  int c = blockIdx.x, h = blockIdx.y, b = blockIdx.z;
  int tid = threadIdx.x;   // 64
  __shared__ float row[24];
  if (tid < 24) {
    const float* p = pdot + (size_t)b * (NHEAD * CH * CH * SCCH) +
                     (((size_t)h * CH + c) * CH + tid) * SCCH;
    float s = 0.f;
#pragma unroll
    for (int i = 0; i < SCCH; ++i) s += p[i];
    const float* pq = qss + (((size_t)b * NHEAD + h) * CH + c) * SCCH;
    const float* pk = kss + (((size_t)b * NHEAD + h) * CH + tid) * SCCH;
    float sq = 0.f, sk = 0.f;
#pragma unroll
    for (int i = 0; i < SCCH; ++i) { sq += pq[i]; sk += pk[i]; }
    float rq = 1.f / fmaxf(sqrtf(sq), 1e-12f);
    float rk = 1.f / fmaxf(sqrtf(sk), 1e-12f);
    row[tid] = s * rq * rk * temp[h];
  }
  __syncthreads();
  if (tid < 24) {
    float mx = -1e30f;
    for (int d = 0; d < 24; ++d) mx = fmaxf(mx, row[d]);
    float sum = 0.f;
    for (int d = 0; d < 24; ++d) sum += expf(row[d] - mx);
    atn[((size_t)b * NHEAD + h) * 576 + c * CH + tid] = expf(row[tid] - mx) / sum;
  }
}

// ---------------- PV -> pvt bf16 [b][s][192] (batched z) ----------------
__global__ __launch_bounds__(256) void attn_pv_bf16(const short* __restrict__ D,
                                                    const float* __restrict__ atn,
                                                    short* __restrict__ pvt) {
  int nb = blockIdx.x, h = blockIdx.y, b = blockIdx.z;
  __shared__ float aL[24][24];
  int tid = threadIdx.x;
  const float* ab = atn + ((size_t)b * NHEAD + h) * 576;
  for (int i = tid; i < 576; i += 256) aL[i / 24][i % 24] = ab[i];
  __syncthreads();
  int n = nb * 256 + tid;
  const short* vb = D + ((size_t)b * OC3 + 2 * CDIM + h * CH) * SSP + n;
  float vv[24];
#pragma unroll
  for (int d = 0; d < 24; ++d) vv[d] = bf2f(vb[(size_t)d * SSP]);
  short* ob = pvt + (size_t)b * SSP * CDIM + (size_t)n * CDIM + h * CH;
  bf16x8 o0, o1, o2;
#pragma unroll
  for (int cc = 0; cc < 24; ++cc) {
    float s = 0.f;
#pragma unroll
    for (int d = 0; d < 24; ++d) s += aL[cc][d] * vv[d];
    short bv = f2bf(s);
    if (cc < 8) o0[cc & 7] = bv; else if (cc < 16) o1[cc & 7] = bv; else o2[cc & 7] = bv;
  }
  *(bf16x8*)(ob) = o0;
  *(bf16x8*)(ob + 8) = o1;
  *(bf16x8*)(ob + 16) = o2;
}

// ---------------- fused MLP v3 (measured 300us) + bf16 x1 residual ----------------
__global__ __launch_bounds__(512) void mlp_fused(const short* __restrict__ y2,
                                                 const short* __restrict__ w1,
                                                 const short* __restrict__ w2,
                                                 const float* __restrict__ b1,
                                                 const float* __restrict__ b2,
                                                 const short* __restrict__ x1w,
                                                 float* __restrict__ out) {
  __shared__ short y2s[128 * 200];   // 51200 B
  __shared__ short w1s[64 * 200];    // 25600 B
  __shared__ short w2s[192 * 72];    // 27648 B
  __shared__ short h1s[128 * 72];    // 18432 B  (total 120 KiB)
  const int tid = threadIdx.x;
  const int m0 = blockIdx.x * 128;
  const int w = tid >> 6, lane = tid & 63;
  const int r16 = lane & 15, kg = lane >> 4;
  const int wm = w >> 1, wn = w & 1;

  const int u0 = tid, u1 = 512 + tid, u2 = 1024 + tid;
  const int s1r[3] = {u0 / 24, u1 / 24, u2 / 24};
  const int s1c[3] = {u0 % 24, u1 % 24, u2 % 24};
  const int s2r[3] = {u0 / 8, u1 / 8, u2 / 8};
  const int s2c[3] = {u0 % 8, u1 % 8, u2 % 8};

#pragma unroll
  for (int it = 0; it < 6; ++it) {
    int u = it * 512 + tid;
    int row = u / 24, cx = u % 24;
    *(bf16x8*)(&y2s[row * 200 + cx * 8]) =
        *(const bf16x8*)(y2 + (size_t)(m0 + row) * CDIM + cx * 8);
  }
#pragma unroll
  for (int it = 0; it < 3; ++it) {
    *(bf16x8*)(&w1s[s1r[it] * 200 + s1c[it] * 8]) =
        *(const bf16x8*)(w1 + (size_t)s1r[it] * CDIM + s1c[it] * 8);
    *(bf16x8*)(&w2s[s2r[it] * 72 + s2c[it] * 8]) =
        *(const bf16x8*)(w2 + (size_t)s2r[it] * HIDF + s2c[it] * 8);
  }
  __syncthreads();

  f32x4 bacc[2][6] = {};
  bf16x8 rw1[3], rw2[3];

  for (int hc = 0; hc < 12; ++hc) {
    if (hc < 11) {
#pragma unroll
      for (int it = 0; it < 3; ++it) {
        rw1[it] = *(const bf16x8*)(w1 + (size_t)((hc + 1) * 64 + s1r[it]) * CDIM + s1c[it] * 8);
        rw2[it] = *(const bf16x8*)(w2 + (size_t)s2r[it] * HIDF + (hc + 1) * 64 + s2c[it] * 8);
      }
    }
    f32x4 pacc[2][2] = {};
#pragma unroll
    for (int ks = 0; ks < 6; ++ks) {
      bf16x8 af[2], bg[2];
#pragma unroll
      for (int i = 0; i < 2; ++i)
        af[i] = *(bf16x8*)(&y2s[(wm * 32 + i * 16 + r16) * 200 + ks * 32 + kg * 8]);
#pragma unroll
      for (int j = 0; j < 2; ++j)
        bg[j] = *(bf16x8*)(&w1s[(wn * 32 + j * 16 + r16) * 200 + ks * 32 + kg * 8]);
#pragma unroll
      for (int i = 0; i < 2; ++i)
#pragma unroll
        for (int j = 0; j < 2; ++j)
          pacc[i][j] = __builtin_amdgcn_mfma_f32_16x16x32_bf16(bg[j], af[i], pacc[i][j], 0, 0, 0);
    }
#pragma unroll
    for (int i = 0; i < 2; ++i) {
      int mr = wm * 32 + i * 16 + r16;
#pragma unroll
      for (int j = 0; j < 2; ++j) {
        int hid0 = wn * 32 + j * 16 + kg * 4;
        bf16x4 pk;
#pragma unroll
        for (int t = 0; t < 4; ++t) {
          float v = pacc[i][j][t] + b1[hc * 64 + hid0 + t];
          v = 0.5f * v * (1.f + erff(v * 0.70710678118654752f));
          pk[t] = f2bf(v);
        }
        *(bf16x4*)(&h1s[mr * 72 + hid0]) = pk;
      }
    }
    __syncthreads();

#pragma unroll
    for (int ks = 0; ks < 2; ++ks) {
      bf16x8 a2[2];
#pragma unroll
      for (int i = 0; i < 2; ++i)
        a2[i] = *(bf16x8*)(&h1s[(wm * 32 + i * 16 + r16) * 72 + ks * 32 + kg * 8]);
#pragma unroll
      for (int j = 0; j < 6; ++j) {
        bf16x8 b2g = *(bf16x8*)(&w2s[(wn * 96 + j * 16 + r16) * 72 + ks * 32 + kg * 8]);
#pragma unroll
        for (int i = 0; i < 2; ++i)
          bacc[i][j] = __builtin_amdgcn_mfma_f32_16x16x32_bf16(a2[i], b2g, bacc[i][j], 0, 0, 0);
      }
    }
    __syncthreads();

    if (hc < 11) {
#pragma unroll
      for (int it = 0; it < 3; ++it) {
        *(bf16x8*)(&w1s[s1r[it] * 200 + s1c[it] * 8]) = rw1[it];
        *(bf16x8*)(&w2s[s2r[it] * 72 + s2c[it] * 8]) = rw2[it];
      }
      __syncthreads();
    }
  }

#pragma unroll
  for (int i = 0; i < 2; ++i)
#pragma unroll
    for (int j = 0; j < 6; ++j)
#pragma unroll
      for (int t = 0; t < 4; ++t) {
        int m = m0 + wm * 32 + i * 16 + kg * 4 + t;
        int n = wn * 96 + j * 16 + r16;
        size_t idx = (size_t)m * CDIM + n;
        out[idx] = bacc[i][j][t] + b2[n] + bf2f(x1w[idx]);
      }
}

extern "C" void kernel_launch(void* const* d_in, const int* in_sizes, int n_in,
                              void* d_out, int out_size, void* d_ws, size_t ws_size,
                              hipStream_t stream) {
  const float* x      = (const float*)d_in[0];
  const float* ln1_w  = (const float*)d_in[1];
  const float* ln1_b  = (const float*)d_in[2];
  const float* temp   = (const float*)d_in[3];
  const float* qkv_w  = (const float*)d_in[4];
  const float* dw_w   = (const float*)d_in[5];
  const float* proj_w = (const float*)d_in[6];
  const float* ln2_w  = (const float*)d_in[7];
  const float* ln2_b  = (const float*)d_in[8];
  const float* fc1_w  = (const float*)d_in[9];
  const float* fc1_b  = (const float*)d_in[10];
  const float* fc2_w  = (const float*)d_in[11];
  const float* fc2_b  = (const float*)d_in[12];
  float* out = (float*)d_out;

  char* base = (char*)d_ws;
  short* wq  = (short*)base;
  short* wp  = wq + 110592;
  short* w1  = wp + 36864;
  short* w2  = w1 + 147456;
  float* pdot= (float*)(base + 890880);
  float* qss = (float*)(base + 2660352);
  float* kss = (float*)(base + 2734080);
  float* atn = (float*)(base + 2807808);
  short* Dv  = (short*)(base + 4194304);         // [4][576][SSP] bf16 (226.5 MB)
  short* y1t = Dv;                               // [4][SSP][192] overlay (dead before Dv)
  short* x1w = Dv;                               // [4][192][SSP] bf16 overlay (Dv dead after pv)
  short* T   = (short*)(base + 230686720);       // [4][576][SSP] bf16
  short* pvt = T;                                // [4][SSP][192] overlay (T dead after dwconv)
  short* y2  = (short*)(base + 306184192);       // [4][192][SSP] bf16, in dead T tail
  short* xw  = (short*)(base + 457179136);       // [4][192][SSP] bf16 raw x copy

  // weights -> bf16 (one launch)
  cvt_all<<<dim3(1728), 256, 0, stream>>>(qkv_w, proj_w, fc1_w, fc2_w, wq);

  // 1. LN1 -> y1t bf16 [b][s][192] + raw xw bf16 [b][c][s]
  ln1_bf16<<<dim3(SSP / 64, NB), 256, 0, stream>>>(x, ln1_w, ln1_b, y1t, xw);
  // 2. qkv GEMM (M=576,N=SSP,K=192, z=4) -> T bf16
  mfma_gemmx<false, true><<<dim3(SSP / 256, OC3 / 64, NB), 256, 0, stream>>>(
      wq, y1t, nullptr, T, OC3, SSP, CDIM, (long long)SSP * CDIM, (long long)OC3 * SSP);
  // 3. depthwise 3x3 tiled -> Dv bf16
  dwconv_tile<<<dim3(NB * OC3 * 8), 256, 0, stream>>>(T, dw_w, Dv);
  // 4. scores: partial dots + sumsq, then reduce+norm+softmax
  scores_stage1<<<dim3(SCCH, NHEAD, NB), 256, 0, stream>>>(Dv, pdot, qss, kss);
  scores_reduce<<<dim3(CH, NHEAD, NB), 64, 0, stream>>>(pdot, qss, kss, temp, atn);
  // 5. PV -> pvt bf16 [b][s][192]
  attn_pv_bf16<<<dim3(SSP / 256, NHEAD, NB), 256, 0, stream>>>(Dv, atn, pvt);
  // 6+7. proj + residual(xw bf16) + LN2 fused -> x1w bf16, y2 bf16
  proj_ln2<<<dim3(SSP / 64, NB), 256, 0, stream>>>(wp, pvt, xw, ln2_w, ln2_b, x1w, y2);
  // 8. fused MLP v3 + bf16 residual; sole writer of d_out
  mlp_fused<<<dim3(196608 / 128), 512, 0, stream>>>(y2, w1, w2, fc1_b, fc2_b, x1w, out);
}

// Round 16
// 910.283 us; speedup vs baseline: 1.0305x; 1.0305x over previous
//
#include <hip/hip_runtime.h>
#include <math.h>

// TransformerBlock1: b=4, DIM=192, h=256, w=192, HEADS=8, HID=768
#define SSP   49152
#define HDIM  256
#define WDIM  192
#define CDIM  192
#define NHEAD 8
#define CH    24
#define OC3   576
#define HIDF  768
#define NB    4
#define SCCH  24

typedef short bf16x8 __attribute__((ext_vector_type(8)));
typedef short bf16x4 __attribute__((ext_vector_type(4)));
typedef float f32x4  __attribute__((ext_vector_type(4)));

__device__ inline short f2bf(float f) {
  unsigned u = __float_as_uint(f);
  u += 0x7fffu + ((u >> 16) & 1u);
  return (short)(u >> 16);
}
__device__ inline float bf2f(short h) {
  return __uint_as_float(((unsigned)(unsigned short)h) << 16);
}

// async global->LDS 16B: dest is wave-uniform base + lane*16
__device__ inline void gl_lds16(const short* g, short* l) {
  __builtin_amdgcn_global_load_lds(
      (const __attribute__((address_space(1))) unsigned int*)g,
      (__attribute__((address_space(3))) unsigned int*)l, 16, 0, 0);
}

// ---------------- all four weights -> bf16, one launch ----------------
__global__ __launch_bounds__(256) void cvt_all(const float* __restrict__ s0,
                                               const float* __restrict__ s1,
                                               const float* __restrict__ s2,
                                               const float* __restrict__ s3,
                                               short* __restrict__ dst) {
  int i = blockIdx.x * 256 + threadIdx.x;   // < 442368
  float v;
  if (i < 110592)      v = s0[i];
  else if (i < 147456) v = s1[i - 110592];
  else if (i < 294912) v = s2[i - 147456];
  else                 v = s3[i - 294912];
  dst[i] = f2bf(v);
}

// ---------------- LN over channels, single read, batched over y ----------------
// INBF16: input is bf16 [b][c][s]; else fp32. TRANS: out[s][192]; else out[c][s].
template <bool TRANS, bool INBF16>
__global__ __launch_bounds__(256) void ln_bf16(const void* __restrict__ xin,
                                               const float* __restrict__ w,
                                               const float* __restrict__ bia,
                                               short* __restrict__ outp) {
  __shared__ float xs[192][68];
  __shared__ float ps[4][64], pq[4][64], mus[64], rst[64];
  const int tid = threadIdx.x;
  const int s0 = blockIdx.x * 64;
  short* outb = outp + (size_t)blockIdx.y * CDIM * SSP;
  if (INBF16) {
    const short* xb = (const short*)xin + (size_t)blockIdx.y * CDIM * SSP;
#pragma unroll
    for (int it = 0; it < 6; ++it) {
      int u = it * 256 + tid;            // < 1536
      int c = u >> 3, q = u & 7;
      bf16x8 v = *(const bf16x8*)(xb + (size_t)c * SSP + s0 + q * 8);
#pragma unroll
      for (int j = 0; j < 8; ++j) xs[c][q * 8 + j] = bf2f(v[j]);
    }
  } else {
    const float* xb = (const float*)xin + (size_t)blockIdx.y * CDIM * SSP;
#pragma unroll
    for (int it = 0; it < 12; ++it) {
      int u = it * 256 + tid;
      int c = u >> 4, q = u & 15;
      float4 v = *(const float4*)(xb + (size_t)c * SSP + s0 + q * 4);
      *(float4*)&xs[c][q * 4] = v;
    }
  }
  __syncthreads();
  {
    int s = tid & 63, p = tid >> 6;
    float sm = 0.f, sq = 0.f;
    for (int c = p * 48; c < p * 48 + 48; ++c) {
      float v = xs[c][s]; sm += v; sq += v * v;
    }
    ps[p][s] = sm; pq[p][s] = sq;
  }
  __syncthreads();
  if (tid < 64) {
    float sm = ps[0][tid] + ps[1][tid] + ps[2][tid] + ps[3][tid];
    float sq = pq[0][tid] + pq[1][tid] + pq[2][tid] + pq[3][tid];
    float mu = sm * (1.f / CDIM);
    mus[tid] = mu;
    rst[tid] = rsqrtf(sq * (1.f / CDIM) - mu * mu + 1e-5f);
  }
  __syncthreads();
  if (TRANS) {
#pragma unroll
    for (int it = 0; it < 6; ++it) {
      int u = it * 256 + tid;
      int c8 = u >> 6, sr = u & 63;
      float mu = mus[sr], r = rst[sr];
      bf16x8 o;
#pragma unroll
      for (int j = 0; j < 8; ++j) {
        int c = c8 * 8 + j;
        o[j] = f2bf((xs[c][sr] - mu) * r * w[c] + bia[c]);
      }
      *(bf16x8*)(outb + (size_t)(s0 + sr) * CDIM + c8 * 8) = o;
    }
  } else {
#pragma unroll
    for (int it = 0; it < 6; ++it) {
      int u = it * 256 + tid;
      int c = u >> 3, sv = u & 7;
      float wc = w[c], bc = bia[c];
      bf16x8 o;
#pragma unroll
      for (int j = 0; j < 8; ++j) {
        int s = sv * 8 + j;
        o[j] = f2bf((xs[c][s] - mus[s]) * rst[s] * wc + bc);
      }
      *(bf16x8*)(outb + (size_t)c * SSP + s0 + sv * 8) = o;
    }
  }
}

// ---------------- MFMA bf16 GEMM NT (64x256), gl_lds staging, BK=64 ----------------
// C[m][n] = sum_k A[m][k]*B[n][k] (+resid fp32); out fp32 or bf16.
template <bool RESID, bool OUT_BF16>
__global__ __launch_bounds__(256) void mfma_gemmx(
    const short* __restrict__ A, const short* __restrict__ B,
    const float* __restrict__ resid, void* __restrict__ Cv,
    int M, int N, int K, long long strideB, long long strideC) {
  __shared__ short As[2][64 * 32];
  __shared__ short Bs[2][256 * 32];
  const int tid = threadIdx.x;
  const int m0 = blockIdx.y * 64, n0 = blockIdx.x * 256;
  const long long z = blockIdx.z;
  const short* Bz = B + z * strideB;
  const int w = tid >> 6, lane = tid & 63;
  const int r16 = lane & 15, kg = lane >> 4;
  const int arow = tid >> 2, ac4 = tid & 3;

  f32x4 acc[4][4] = {};

  for (int k0 = 0; k0 < K; k0 += 64) {
#pragma unroll
    for (int s = 0; s < 2; ++s) {
      gl_lds16(A + (size_t)(m0 + arow) * K + k0 + s * 32 + ac4 * 8, As[s] + w * 512);
#pragma unroll
      for (int p = 0; p < 4; ++p) {
        int flat = p * 256 + tid;
        int brow = flat >> 2, bc4 = flat & 3;
        gl_lds16(Bz + (size_t)(n0 + brow) * K + k0 + s * 32 + bc4 * 8, Bs[s] + p * 2048 + w * 512);
      }
    }
    __syncthreads();
#pragma unroll
    for (int s = 0; s < 2; ++s) {
      bf16x8 af[4], bfr[4];
#pragma unroll
      for (int i = 0; i < 4; ++i)
        af[i] = *(bf16x8*)(&As[s][(i * 16 + r16) * 32 + kg * 8]);
#pragma unroll
      for (int j = 0; j < 4; ++j)
        bfr[j] = *(bf16x8*)(&Bs[s][(w * 64 + j * 16 + r16) * 32 + kg * 8]);
#pragma unroll
      for (int i = 0; i < 4; ++i)
#pragma unroll
        for (int j = 0; j < 4; ++j)
          acc[i][j] = __builtin_amdgcn_mfma_f32_16x16x32_bf16(af[i], bfr[j], acc[i][j], 0, 0, 0);
    }
    __syncthreads();
  }

  float* Cf = (float*)Cv + z * strideC;
  short* Ch = (short*)Cv + z * strideC;
  const float* R = RESID ? resid + z * strideC : nullptr;
#pragma unroll
  for (int i = 0; i < 4; ++i) {
#pragma unroll
    for (int j = 0; j < 4; ++j) {
#pragma unroll
      for (int t = 0; t < 4; ++t) {
        int m = m0 + i * 16 + kg * 4 + t;
        int n = n0 + w * 64 + j * 16 + r16;
        float v = acc[i][j][t];
        size_t idx = (size_t)m * N + n;
        if (RESID) v += R[idx];
        if (OUT_BF16) Ch[idx] = f2bf(v); else Cf[idx] = v;
      }
    }
  }
}

// ---------------- 3x3 depthwise conv, LDS-tiled, bf16->bf16, batched ----------------
__global__ __launch_bounds__(256) void dwconv_tile(const short* __restrict__ in,
                                                   const float* __restrict__ w9,
                                                   short* __restrict__ out) {
  __shared__ short tile[34][208];
  const int tid = threadIdx.x;
  const int ch = blockIdx.x >> 3;        // b*OC3 + o
  const int slab = blockIdx.x & 7;
  const int o = ch % OC3;
  const int y0 = slab * 32;
  float wr[9];
#pragma unroll
  for (int i = 0; i < 9; ++i) wr[i] = w9[o * 9 + i];
  const short* ip = in + (size_t)ch * SSP;

  if (tid < 34) { tile[tid][7] = 0; tile[tid][200] = 0; }
#pragma unroll
  for (int i = 0; i < 4; ++i) {
    int idx = i * 256 + tid;
    if (idx < 816) {
      int row = idx / 24, cx = idx - row * 24;
      int gy = y0 + row - 1;
      bf16x8 v = {};
      if (gy >= 0 && gy < HDIM) v = *(const bf16x8*)(ip + gy * WDIM + cx * 8);
      *(bf16x8*)(&tile[row][8 + cx * 8]) = v;
    }
  }
  __syncthreads();

  short* op = out + (size_t)ch * SSP;
#pragma unroll
  for (int g = 0; g < 3; ++g) {
    int G = g * 256 + tid;
    int r = G / 24, cx = G - (G / 24) * 24;
    int cb = cx * 8 + 7;
    float a[10], b[10], c[10];
#pragma unroll
    for (int d = 0; d < 10; ++d) {
      a[d] = bf2f(tile[r][cb + d]);
      b[d] = bf2f(tile[r + 1][cb + d]);
      c[d] = bf2f(tile[r + 2][cb + d]);
    }
    bf16x8 ov;
#pragma unroll
    for (int j = 0; j < 8; ++j) {
      float acc = wr[0] * a[j] + wr[1] * a[j + 1] + wr[2] * a[j + 2]
                + wr[3] * b[j] + wr[4] * b[j + 1] + wr[5] * b[j + 2]
                + wr[6] * c[j] + wr[7] * c[j + 1] + wr[8] * c[j + 2];
      ov[j] = f2bf(acc);
    }
    *(bf16x8*)(op + (y0 + r) * WDIM + cx * 8) = ov;
  }
}

// ---------------- scores stage1: partial dots + per-row sumsq chunks (batched z) ----------------
__global__ __launch_bounds__(256) void scores_stage1(const short* __restrict__ D,
                                                     float* __restrict__ pdot,
                                                     float* __restrict__ qss,
                                                     float* __restrict__ kss) {
  int ch = blockIdx.x, h = blockIdx.y, b = blockIdx.z;
  __shared__ float qs[24][260];
  __shared__ float ks[24][260];
  int tid = threadIdx.x;
  int w = tid >> 6, lane = tid & 63;
  int c0 = w * 6;
  float acc[6] = {0.f, 0.f, 0.f, 0.f, 0.f, 0.f};
  float ssacc = 0.f;
  const short* qb = D + ((size_t)b * OC3 + h * CH) * SSP;
  const short* kb = D + ((size_t)b * OC3 + CDIM + h * CH) * SSP;
  for (int it = 0; it < 8; ++it) {
    int s0 = ch * 2048 + it * 256;
#pragma unroll
    for (int p = 0; p < 3; ++p) {
      int u = p * 256 + tid;
      int row = u >> 5, col8 = u & 31;
      bf16x8 qv = *(const bf16x8*)(qb + (size_t)row * SSP + s0 + col8 * 8);
      bf16x8 kv = *(const bf16x8*)(kb + (size_t)row * SSP + s0 + col8 * 8);
#pragma unroll
      for (int j = 0; j < 8; ++j) {
        qs[row][col8 * 8 + j] = bf2f(qv[j]);
        ks[row][col8 * 8 + j] = bf2f(kv[j]);
      }
    }
    __syncthreads();
    if (w < 2 && lane < 24) {
      const float (*src)[260] = (w == 0) ? qs : ks;
      for (int s = 0; s < 256; s += 4) {
        float4 v = *(const float4*)&src[lane][s];
        ssacc += v.x * v.x + v.y * v.y + v.z * v.z + v.w * v.w;
      }
    }
    if (lane < 24) {
      for (int s = 0; s < 256; s += 4) {
        float4 kv = *(float4*)&ks[lane][s];
#pragma unroll
        for (int i = 0; i < 6; ++i) {
          float4 qv = *(float4*)&qs[c0 + i][s];
          acc[i] += qv.x * kv.x + qv.y * kv.y + qv.z * kv.z + qv.w * kv.w;
        }
      }
    }
    __syncthreads();
  }
  if (lane < 24) {
    float* pb = pdot + (size_t)b * (NHEAD * CH * CH * SCCH);
#pragma unroll
    for (int i = 0; i < 6; ++i)
      pb[(((size_t)h * CH + (c0 + i)) * CH + lane) * SCCH + ch] = acc[i];
    if (w == 0) qss[(((size_t)b * NHEAD + h) * CH + lane) * SCCH + ch] = ssacc;
    if (w == 1) kss[(((size_t)b * NHEAD + h) * CH + lane) * SCCH + ch] = ssacc;
  }
}

// ---------------- scores reduce + norms + temperature + softmax (batched z) ----------------
__global__ void scores_reduce(const float* __restrict__ pdot,
                              const float* __restrict__ qss,
                              const float* __restrict__ kss,
                              const float* __restrict__ temp,
                              float* __restrict__ atn) {
  int c = blockIdx.x, h = blockIdx.y, b = blockIdx.z;
  int tid = threadIdx.x;   // 64
  __shared__ float row[24];
  if (tid < 24) {
    const float* p = pdot + (size_t)b * (NHEAD * CH * CH * SCCH) +
                     (((size_t)h * CH + c) * CH + tid) * SCCH;
    float s = 0.f;
#pragma unroll
    for (int i = 0; i < SCCH; ++i) s += p[i];
    const float* pq = qss + (((size_t)b * NHEAD + h) * CH + c) * SCCH;
    const float* pk = kss + (((size_t)b * NHEAD + h) * CH + tid) * SCCH;
    float sq = 0.f, sk = 0.f;
#pragma unroll
    for (int i = 0; i < SCCH; ++i) { sq += pq[i]; sk += pk[i]; }
    float rq = 1.f / fmaxf(sqrtf(sq), 1e-12f);
    float rk = 1.f / fmaxf(sqrtf(sk), 1e-12f);
    row[tid] = s * rq * rk * temp[h];
  }
  __syncthreads();
  if (tid < 24) {
    float mx = -1e30f;
    for (int d = 0; d < 24; ++d) mx = fmaxf(mx, row[d]);
    float sum = 0.f;
    for (int d = 0; d < 24; ++d) sum += expf(row[d] - mx);
    atn[((size_t)b * NHEAD + h) * 576 + c * CH + tid] = expf(row[tid] - mx) / sum;
  }
}

// ---------------- PV -> pvt bf16 [b][s][192] (batched z) ----------------
__global__ __launch_bounds__(256) void attn_pv_bf16(const short* __restrict__ D,
                                                    const float* __restrict__ atn,
                                                    short* __restrict__ pvt) {
  int nb = blockIdx.x, h = blockIdx.y, b = blockIdx.z;
  __shared__ float aL[24][24];
  int tid = threadIdx.x;
  const float* ab = atn + ((size_t)b * NHEAD + h) * 576;
  for (int i = tid; i < 576; i += 256) aL[i / 24][i % 24] = ab[i];
  __syncthreads();
  int n = nb * 256 + tid;
  const short* vb = D + ((size_t)b * OC3 + 2 * CDIM + h * CH) * SSP + n;
  float vv[24];
#pragma unroll
  for (int d = 0; d < 24; ++d) vv[d] = bf2f(vb[(size_t)d * SSP]);
  short* ob = pvt + (size_t)b * SSP * CDIM + (size_t)n * CDIM + h * CH;
  bf16x8 o0, o1, o2;
#pragma unroll
  for (int cc = 0; cc < 24; ++cc) {
    float s = 0.f;
#pragma unroll
    for (int d = 0; d < 24; ++d) s += aL[cc][d] * vv[d];
    short bv = f2bf(s);
    if (cc < 8) o0[cc & 7] = bv; else if (cc < 16) o1[cc & 7] = bv; else o2[cc & 7] = bv;
  }
  *(bf16x8*)(ob) = o0;
  *(bf16x8*)(ob + 8) = o1;
  *(bf16x8*)(ob + 16) = o2;
}

// ---------------- fused MLP v3 + bf16 x1 residual + fast gelu ----------------
// out[m][0..191] = gelu(y2[m][:] @ w1^T + b1) @ w2^T + b2 + x1w[m][:] ; 128 rows/block, 512 thr.
__global__ __launch_bounds__(512) void mlp_fused(const short* __restrict__ y2,
                                                 const short* __restrict__ w1,
                                                 const short* __restrict__ w2,
                                                 const float* __restrict__ b1,
                                                 const float* __restrict__ b2,
                                                 const short* __restrict__ x1w,
                                                 float* __restrict__ out) {
  __shared__ short y2s[128 * 200];   // 51200 B
  __shared__ short w1s[64 * 200];    // 25600 B
  __shared__ short w2s[192 * 72];    // 27648 B
  __shared__ short h1s[128 * 72];    // 18432 B  (total 120 KiB)
  const int tid = threadIdx.x;
  const int m0 = blockIdx.x * 128;
  const int w = tid >> 6, lane = tid & 63;
  const int r16 = lane & 15, kg = lane >> 4;
  const int wm = w >> 1, wn = w & 1;

  const int u0 = tid, u1 = 512 + tid, u2 = 1024 + tid;
  const int s1r[3] = {u0 / 24, u1 / 24, u2 / 24};
  const int s1c[3] = {u0 % 24, u1 % 24, u2 % 24};
  const int s2r[3] = {u0 / 8, u1 / 8, u2 / 8};
  const int s2c[3] = {u0 % 8, u1 % 8, u2 % 8};

  // stage y2 tile once: 128 rows x 24 vec8 chunks = 3072 -> 6 per thread
#pragma unroll
  for (int it = 0; it < 6; ++it) {
    int u = it * 512 + tid;
    int row = u / 24, cx = u % 24;
    *(bf16x8*)(&y2s[row * 200 + cx * 8]) =
        *(const bf16x8*)(y2 + (size_t)(m0 + row) * CDIM + cx * 8);
  }
  // stage chunk-0 weights
#pragma unroll
  for (int it = 0; it < 3; ++it) {
    *(bf16x8*)(&w1s[s1r[it] * 200 + s1c[it] * 8]) =
        *(const bf16x8*)(w1 + (size_t)s1r[it] * CDIM + s1c[it] * 8);
    *(bf16x8*)(&w2s[s2r[it] * 72 + s2c[it] * 8]) =
        *(const bf16x8*)(w2 + (size_t)s2r[it] * HIDF + s2c[it] * 8);
  }
  __syncthreads();

  f32x4 bacc[2][6] = {};
  bf16x8 rw1[3], rw2[3];

  for (int hc = 0; hc < 12; ++hc) {
    if (hc < 11) {     // issue next chunk's weight loads early
#pragma unroll
      for (int it = 0; it < 3; ++it) {
        rw1[it] = *(const bf16x8*)(w1 + (size_t)((hc + 1) * 64 + s1r[it]) * CDIM + s1c[it] * 8);
        rw2[it] = *(const bf16x8*)(w2 + (size_t)s2r[it] * HIDF + (hc + 1) * 64 + s2c[it] * 8);
      }
    }
    // phase A (swapped): D[hid][m]
    f32x4 pacc[2][2] = {};
#pragma unroll
    for (int ks = 0; ks < 6; ++ks) {
      bf16x8 af[2], bg[2];
#pragma unroll
      for (int i = 0; i < 2; ++i)
        af[i] = *(bf16x8*)(&y2s[(wm * 32 + i * 16 + r16) * 200 + ks * 32 + kg * 8]);
#pragma unroll
      for (int j = 0; j < 2; ++j)
        bg[j] = *(bf16x8*)(&w1s[(wn * 32 + j * 16 + r16) * 200 + ks * 32 + kg * 8]);
#pragma unroll
      for (int i = 0; i < 2; ++i)
#pragma unroll
        for (int j = 0; j < 2; ++j)
          pacc[i][j] = __builtin_amdgcn_mfma_f32_16x16x32_bf16(bg[j], af[i], pacc[i][j], 0, 0, 0);
    }
    // bias + FAST gelu (tanh form, hw exp) -> h1s packed 8B writes
#pragma unroll
    for (int i = 0; i < 2; ++i) {
      int mr = wm * 32 + i * 16 + r16;
#pragma unroll
      for (int j = 0; j < 2; ++j) {
        int hid0 = wn * 32 + j * 16 + kg * 4;
        bf16x4 pk;
#pragma unroll
        for (int t = 0; t < 4; ++t) {
          float v = pacc[i][j][t] + b1[hc * 64 + hid0 + t];
          float u = v * (0.7978845608f + 0.0356774081f * v * v);
          v = v / (1.f + __expf(-2.f * u));
          pk[t] = f2bf(v);
        }
        *(bf16x4*)(&h1s[mr * 72 + hid0]) = pk;
      }
    }
    __syncthreads();   // h1s visible

    // phase B: bacc += h1s @ w2s^T
#pragma unroll
    for (int ks = 0; ks < 2; ++ks) {
      bf16x8 a2[2];
#pragma unroll
      for (int i = 0; i < 2; ++i)
        a2[i] = *(bf16x8*)(&h1s[(wm * 32 + i * 16 + r16) * 72 + ks * 32 + kg * 8]);
#pragma unroll
      for (int j = 0; j < 6; ++j) {
        bf16x8 b2g = *(bf16x8*)(&w2s[(wn * 96 + j * 16 + r16) * 72 + ks * 32 + kg * 8]);
#pragma unroll
        for (int i = 0; i < 2; ++i)
          bacc[i][j] = __builtin_amdgcn_mfma_f32_16x16x32_bf16(a2[i], b2g, bacc[i][j], 0, 0, 0);
      }
    }
    __syncthreads();   // all reads done

    // write prefetched regs -> LDS for next chunk
    if (hc < 11) {
#pragma unroll
      for (int it = 0; it < 3; ++it) {
        *(bf16x8*)(&w1s[s1r[it] * 200 + s1c[it] * 8]) = rw1[it];
        *(bf16x8*)(&w2s[s2r[it] * 72 + s2c[it] * 8]) = rw2[it];
      }
      __syncthreads();
    }
  }

  // epilogue: out = bacc + b2 + x1(bf16) — sole writer of d_out
#pragma unroll
  for (int i = 0; i < 2; ++i)
#pragma unroll
    for (int j = 0; j < 6; ++j)
#pragma unroll
      for (int t = 0; t < 4; ++t) {
        int m = m0 + wm * 32 + i * 16 + kg * 4 + t;
        int n = wn * 96 + j * 16 + r16;
        size_t idx = (size_t)m * CDIM + n;
        out[idx] = bacc[i][j][t] + b2[n] + bf2f(x1w[idx]);
      }
}

extern "C" void kernel_launch(void* const* d_in, const int* in_sizes, int n_in,
                              void* d_out, int out_size, void* d_ws, size_t ws_size,
                              hipStream_t stream) {
  const float* x      = (const float*)d_in[0];
  const float* ln1_w  = (const float*)d_in[1];
  const float* ln1_b  = (const float*)d_in[2];
  const float* temp   = (const float*)d_in[3];
  const float* qkv_w  = (const float*)d_in[4];
  const float* dw_w   = (const float*)d_in[5];
  const float* proj_w = (const float*)d_in[6];
  const float* ln2_w  = (const float*)d_in[7];
  const float* ln2_b  = (const float*)d_in[8];
  const float* fc1_w  = (const float*)d_in[9];
  const float* fc1_b  = (const float*)d_in[10];
  const float* fc2_w  = (const float*)d_in[11];
  const float* fc2_b  = (const float*)d_in[12];
  float* out = (float*)d_out;

  char* base = (char*)d_ws;
  short* wq  = (short*)base;
  short* wp  = wq + 110592;
  short* w1  = wp + 36864;
  short* w2  = w1 + 147456;
  float* pdot= (float*)(base + 890880);
  float* qss = (float*)(base + 2660352);
  float* kss = (float*)(base + 2734080);
  float* atn = (float*)(base + 2807808);
  short* Dv  = (short*)(base + 4194304);         // [4][576][SSP] bf16 (226.5 MB)
  short* y1t = Dv;                               // [4][SSP][192] overlay (dead before Dv)
  short* x1w = Dv;                               // [4][192][SSP] bf16 overlay (Dv dead after pv)
  short* T   = (short*)(base + 230686720);       // [4][576][SSP] bf16
  short* pvt = T;                                // overlay (T dead after dwconv)
  short* y2  = (short*)(base + 457179136);       // [4][192][SSP] bf16

  // weights -> bf16 (one launch)
  cvt_all<<<dim3(1728), 256, 0, stream>>>(qkv_w, proj_w, fc1_w, fc2_w, wq);

  // 1. LN1 -> y1t bf16 [b][s][192] (single-read)
  ln_bf16<true, false><<<dim3(SSP / 64, NB), 256, 0, stream>>>(x, ln1_w, ln1_b, y1t);
  // 2. qkv GEMM (M=576,N=SSP,K=192, z=4) -> T bf16
  mfma_gemmx<false, true><<<dim3(SSP / 256, OC3 / 64, NB), 256, 0, stream>>>(
      wq, y1t, nullptr, T, OC3, SSP, CDIM, (long long)SSP * CDIM, (long long)OC3 * SSP);
  // 3. depthwise 3x3 tiled -> Dv bf16
  dwconv_tile<<<dim3(NB * OC3 * 8), 256, 0, stream>>>(T, dw_w, Dv);
  // 4. scores: partial dots + sumsq, then reduce+norm+softmax
  scores_stage1<<<dim3(SCCH, NHEAD, NB), 256, 0, stream>>>(Dv, pdot, qss, kss);
  scores_reduce<<<dim3(CH, NHEAD, NB), 64, 0, stream>>>(pdot, qss, kss, temp, atn);
  // 5. PV -> pvt bf16 [b][s][192]
  attn_pv_bf16<<<dim3(SSP / 256, NHEAD, NB), 256, 0, stream>>>(Dv, atn, pvt);
  // 6. x1 = proj @ pv + x -> x1w (bf16, overlays dead Dv)
  mfma_gemmx<true, true><<<dim3(SSP / 256, CDIM / 64, NB), 256, 0, stream>>>(
      wp, pvt, x, x1w, CDIM, SSP, CDIM, (long long)SSP * CDIM, (long long)CDIM * SSP);
  // 7. LN2 -> y2 bf16 [b][c][s] (bf16 input, single-read)
  ln_bf16<false, true><<<dim3(SSP / 64, NB), 256, 0, stream>>>(x1w, ln2_w, ln2_b, y2);
  // 8. fused MLP v3 (fast gelu) + bf16 residual; sole writer of d_out
  mlp_fused<<<dim3(196608 / 128), 512, 0, stream>>>(y2, w1, w2, fc1_b, fc2_b, x1w, out);
}

// Round 17
// 908.640 us; speedup vs baseline: 1.0323x; 1.0018x over previous
//
#include <hip/hip_runtime.h>
#include <math.h>

// TransformerBlock1: b=4, DIM=192, h=256, w=192, HEADS=8, HID=768
#define SSP   49152
#define HDIM  256
#define WDIM  192
#define CDIM  192
#define NHEAD 8
#define CH    24
#define OC3   576
#define HIDF  768
#define NB    4
#define SCCH  24
// mlp LDS row strides (shorts): step ≡ 6 words (mod 32) -> ~conflict-free
#define S1    204
#define S2    76

typedef short bf16x8 __attribute__((ext_vector_type(8)));
typedef short bf16x4 __attribute__((ext_vector_type(4)));
typedef float f32x4  __attribute__((ext_vector_type(4)));

__device__ inline short f2bf(float f) {
  unsigned u = __float_as_uint(f);
  u += 0x7fffu + ((u >> 16) & 1u);
  return (short)(u >> 16);
}
__device__ inline float bf2f(short h) {
  return __uint_as_float(((unsigned)(unsigned short)h) << 16);
}

// async global->LDS 16B: dest is wave-uniform base + lane*16
__device__ inline void gl_lds16(const short* g, short* l) {
  __builtin_amdgcn_global_load_lds(
      (const __attribute__((address_space(1))) unsigned int*)g,
      (__attribute__((address_space(3))) unsigned int*)l, 16, 0, 0);
}

// ---------------- all four weights -> bf16, one launch ----------------
__global__ __launch_bounds__(256) void cvt_all(const float* __restrict__ s0,
                                               const float* __restrict__ s1,
                                               const float* __restrict__ s2,
                                               const float* __restrict__ s3,
                                               short* __restrict__ dst) {
  int i = blockIdx.x * 256 + threadIdx.x;   // < 442368
  float v;
  if (i < 110592)      v = s0[i];
  else if (i < 147456) v = s1[i - 110592];
  else if (i < 294912) v = s2[i - 147456];
  else                 v = s3[i - 294912];
  dst[i] = f2bf(v);
}

// ---------------- LN over channels, single read, batched over y ----------------
// INBF16: input is bf16 [b][c][s]; else fp32. TRANS: out[s][192]; else out[c][s].
template <bool TRANS, bool INBF16>
__global__ __launch_bounds__(256) void ln_bf16(const void* __restrict__ xin,
                                               const float* __restrict__ w,
                                               const float* __restrict__ bia,
                                               short* __restrict__ outp) {
  __shared__ float xs[192][68];
  __shared__ float ps[4][64], pq[4][64], mus[64], rst[64];
  const int tid = threadIdx.x;
  const int s0 = blockIdx.x * 64;
  short* outb = outp + (size_t)blockIdx.y * CDIM * SSP;
  if (INBF16) {
    const short* xb = (const short*)xin + (size_t)blockIdx.y * CDIM * SSP;
#pragma unroll
    for (int it = 0; it < 6; ++it) {
      int u = it * 256 + tid;            // < 1536
      int c = u >> 3, q = u & 7;
      bf16x8 v = *(const bf16x8*)(xb + (size_t)c * SSP + s0 + q * 8);
#pragma unroll
      for (int j = 0; j < 8; ++j) xs[c][q * 8 + j] = bf2f(v[j]);
    }
  } else {
    const float* xb = (const float*)xin + (size_t)blockIdx.y * CDIM * SSP;
#pragma unroll
    for (int it = 0; it < 12; ++it) {
      int u = it * 256 + tid;
      int c = u >> 4, q = u & 15;
      float4 v = *(const float4*)(xb + (size_t)c * SSP + s0 + q * 4);
      *(float4*)&xs[c][q * 4] = v;
    }
  }
  __syncthreads();
  {
    int s = tid & 63, p = tid >> 6;
    float sm = 0.f, sq = 0.f;
    for (int c = p * 48; c < p * 48 + 48; ++c) {
      float v = xs[c][s]; sm += v; sq += v * v;
    }
    ps[p][s] = sm; pq[p][s] = sq;
  }
  __syncthreads();
  if (tid < 64) {
    float sm = ps[0][tid] + ps[1][tid] + ps[2][tid] + ps[3][tid];
    float sq = pq[0][tid] + pq[1][tid] + pq[2][tid] + pq[3][tid];
    float mu = sm * (1.f / CDIM);
    mus[tid] = mu;
    rst[tid] = rsqrtf(sq * (1.f / CDIM) - mu * mu + 1e-5f);
  }
  __syncthreads();
  if (TRANS) {
#pragma unroll
    for (int it = 0; it < 6; ++it) {
      int u = it * 256 + tid;
      int c8 = u >> 6, sr = u & 63;
      float mu = mus[sr], r = rst[sr];
      bf16x8 o;
#pragma unroll
      for (int j = 0; j < 8; ++j) {
        int c = c8 * 8 + j;
        o[j] = f2bf((xs[c][sr] - mu) * r * w[c] + bia[c]);
      }
      *(bf16x8*)(outb + (size_t)(s0 + sr) * CDIM + c8 * 8) = o;
    }
  } else {
#pragma unroll
    for (int it = 0; it < 6; ++it) {
      int u = it * 256 + tid;
      int c = u >> 3, sv = u & 7;
      float wc = w[c], bc = bia[c];
      bf16x8 o;
#pragma unroll
      for (int j = 0; j < 8; ++j) {
        int s = sv * 8 + j;
        o[j] = f2bf((xs[c][s] - mus[s]) * rst[s] * wc + bc);
      }
      *(bf16x8*)(outb + (size_t)c * SSP + s0 + sv * 8) = o;
    }
  }
}

// ---------------- MFMA bf16 GEMM NT (64x256), gl_lds staging, BK=64 ----------------
// C[m][n] = sum_k A[m][k]*B[n][k] (+resid fp32); out fp32 or bf16.
template <bool RESID, bool OUT_BF16>
__global__ __launch_bounds__(256) void mfma_gemmx(
    const short* __restrict__ A, const short* __restrict__ B,
    const float* __restrict__ resid, void* __restrict__ Cv,
    int M, int N, int K, long long strideB, long long strideC) {
  __shared__ short As[2][64 * 32];
  __shared__ short Bs[2][256 * 32];
  const int tid = threadIdx.x;
  const int m0 = blockIdx.y * 64, n0 = blockIdx.x * 256;
  const long long z = blockIdx.z;
  const short* Bz = B + z * strideB;
  const int w = tid >> 6, lane = tid & 63;
  const int r16 = lane & 15, kg = lane >> 4;
  const int arow = tid >> 2, ac4 = tid & 3;

  f32x4 acc[4][4] = {};

  for (int k0 = 0; k0 < K; k0 += 64) {
#pragma unroll
    for (int s = 0; s < 2; ++s) {
      gl_lds16(A + (size_t)(m0 + arow) * K + k0 + s * 32 + ac4 * 8, As[s] + w * 512);
#pragma unroll
      for (int p = 0; p < 4; ++p) {
        int flat = p * 256 + tid;
        int brow = flat >> 2, bc4 = flat & 3;
        gl_lds16(Bz + (size_t)(n0 + brow) * K + k0 + s * 32 + bc4 * 8, Bs[s] + p * 2048 + w * 512);
      }
    }
    __syncthreads();
#pragma unroll
    for (int s = 0; s < 2; ++s) {
      bf16x8 af[4], bfr[4];
#pragma unroll
      for (int i = 0; i < 4; ++i)
        af[i] = *(bf16x8*)(&As[s][(i * 16 + r16) * 32 + kg * 8]);
#pragma unroll
      for (int j = 0; j < 4; ++j)
        bfr[j] = *(bf16x8*)(&Bs[s][(w * 64 + j * 16 + r16) * 32 + kg * 8]);
#pragma unroll
      for (int i = 0; i < 4; ++i)
#pragma unroll
        for (int j = 0; j < 4; ++j)
          acc[i][j] = __builtin_amdgcn_mfma_f32_16x16x32_bf16(af[i], bfr[j], acc[i][j], 0, 0, 0);
    }
    __syncthreads();
  }

  float* Cf = (float*)Cv + z * strideC;
  short* Ch = (short*)Cv + z * strideC;
  const float* R = RESID ? resid + z * strideC : nullptr;
#pragma unroll
  for (int i = 0; i < 4; ++i) {
#pragma unroll
    for (int j = 0; j < 4; ++j) {
#pragma unroll
      for (int t = 0; t < 4; ++t) {
        int m = m0 + i * 16 + kg * 4 + t;
        int n = n0 + w * 64 + j * 16 + r16;
        float v = acc[i][j][t];
        size_t idx = (size_t)m * N + n;
        if (RESID) v += R[idx];
        if (OUT_BF16) Ch[idx] = f2bf(v); else Cf[idx] = v;
      }
    }
  }
}

// ---------------- 3x3 depthwise conv, LDS-tiled, bf16->bf16, batched ----------------
__global__ __launch_bounds__(256) void dwconv_tile(const short* __restrict__ in,
                                                   const float* __restrict__ w9,
                                                   short* __restrict__ out) {
  __shared__ short tile[34][208];
  const int tid = threadIdx.x;
  const int ch = blockIdx.x >> 3;        // b*OC3 + o
  const int slab = blockIdx.x & 7;
  const int o = ch % OC3;
  const int y0 = slab * 32;
  float wr[9];
#pragma unroll
  for (int i = 0; i < 9; ++i) wr[i] = w9[o * 9 + i];
  const short* ip = in + (size_t)ch * SSP;

  if (tid < 34) { tile[tid][7] = 0; tile[tid][200] = 0; }
#pragma unroll
  for (int i = 0; i < 4; ++i) {
    int idx = i * 256 + tid;
    if (idx < 816) {
      int row = idx / 24, cx = idx - row * 24;
      int gy = y0 + row - 1;
      bf16x8 v = {};
      if (gy >= 0 && gy < HDIM) v = *(const bf16x8*)(ip + gy * WDIM + cx * 8);
      *(bf16x8*)(&tile[row][8 + cx * 8]) = v;
    }
  }
  __syncthreads();

  short* op = out + (size_t)ch * SSP;
#pragma unroll
  for (int g = 0; g < 3; ++g) {
    int G = g * 256 + tid;
    int r = G / 24, cx = G - (G / 24) * 24;
    int cb = cx * 8 + 7;
    float a[10], b[10], c[10];
#pragma unroll
    for (int d = 0; d < 10; ++d) {
      a[d] = bf2f(tile[r][cb + d]);
      b[d] = bf2f(tile[r + 1][cb + d]);
      c[d] = bf2f(tile[r + 2][cb + d]);
    }
    bf16x8 ov;
#pragma unroll
    for (int j = 0; j < 8; ++j) {
      float acc = wr[0] * a[j] + wr[1] * a[j + 1] + wr[2] * a[j + 2]
                + wr[3] * b[j] + wr[4] * b[j + 1] + wr[5] * b[j + 2]
                + wr[6] * c[j] + wr[7] * c[j + 1] + wr[8] * c[j + 2];
      ov[j] = f2bf(acc);
    }
    *(bf16x8*)(op + (y0 + r) * WDIM + cx * 8) = ov;
  }
}

// ---------------- scores stage1: partial dots + per-row sumsq chunks (batched z) ----------------
__global__ __launch_bounds__(256) void scores_stage1(const short* __restrict__ D,
                                                     float* __restrict__ pdot,
                                                     float* __restrict__ qss,
                                                     float* __restrict__ kss) {
  int ch = blockIdx.x, h = blockIdx.y, b = blockIdx.z;
  __shared__ float qs[24][260];
  __shared__ float ks[24][260];
  int tid = threadIdx.x;
  int w = tid >> 6, lane = tid & 63;
  int c0 = w * 6;
  float acc[6] = {0.f, 0.f, 0.f, 0.f, 0.f, 0.f};
  float ssacc = 0.f;
  const short* qb = D + ((size_t)b * OC3 + h * CH) * SSP;
  const short* kb = D + ((size_t)b * OC3 + CDIM + h * CH) * SSP;
  for (int it = 0; it < 8; ++it) {
    int s0 = ch * 2048 + it * 256;
#pragma unroll
    for (int p = 0; p < 3; ++p) {
      int u = p * 256 + tid;
      int row = u >> 5, col8 = u & 31;
      bf16x8 qv = *(const bf16x8*)(qb + (size_t)row * SSP + s0 + col8 * 8);
      bf16x8 kv = *(const bf16x8*)(kb + (size_t)row * SSP + s0 + col8 * 8);
#pragma unroll
      for (int j = 0; j < 8; ++j) {
        qs[row][col8 * 8 + j] = bf2f(qv[j]);
        ks[row][col8 * 8 + j] = bf2f(kv[j]);
      }
    }
    __syncthreads();
    if (w < 2 && lane < 24) {
      const float (*src)[260] = (w == 0) ? qs : ks;
      for (int s = 0; s < 256; s += 4) {
        float4 v = *(const float4*)&src[lane][s];
        ssacc += v.x * v.x + v.y * v.y + v.z * v.z + v.w * v.w;
      }
    }
    if (lane < 24) {
      for (int s = 0; s < 256; s += 4) {
        float4 kv = *(float4*)&ks[lane][s];
#pragma unroll
        for (int i = 0; i < 6; ++i) {
          float4 qv = *(float4*)&qs[c0 + i][s];
          acc[i] += qv.x * kv.x + qv.y * kv.y + qv.z * kv.z + qv.w * kv.w;
        }
      }
    }
    __syncthreads();
  }
  if (lane < 24) {
    float* pb = pdot + (size_t)b * (NHEAD * CH * CH * SCCH);
#pragma unroll
    for (int i = 0; i < 6; ++i)
      pb[(((size_t)h * CH + (c0 + i)) * CH + lane) * SCCH + ch] = acc[i];
    if (w == 0) qss[(((size_t)b * NHEAD + h) * CH + lane) * SCCH + ch] = ssacc;
    if (w == 1) kss[(((size_t)b * NHEAD + h) * CH + lane) * SCCH + ch] = ssacc;
  }
}

// ---------------- scores reduce + norms + temperature + softmax (batched z) ----------------
__global__ void scores_reduce(const float* __restrict__ pdot,
                              const float* __restrict__ qss,
                              const float* __restrict__ kss,
                              const float* __restrict__ temp,
                              float* __restrict__ atn) {
  int c = blockIdx.x, h = blockIdx.y, b = blockIdx.z;
  int tid = threadIdx.x;   // 64
  __shared__ float row[24];
  if (tid < 24) {
    const float* p = pdot + (size_t)b * (NHEAD * CH * CH * SCCH) +
                     (((size_t)h * CH + c) * CH + tid) * SCCH;
    float s = 0.f;
#pragma unroll
    for (int i = 0; i < SCCH; ++i) s += p[i];
    const float* pq = qss + (((size_t)b * NHEAD + h) * CH + c) * SCCH;
    const float* pk = kss + (((size_t)b * NHEAD + h) * CH + tid) * SCCH;
    float sq = 0.f, sk = 0.f;
#pragma unroll
    for (int i = 0; i < SCCH; ++i) { sq += pq[i]; sk += pk[i]; }
    float rq = 1.f / fmaxf(sqrtf(sq), 1e-12f);
    float rk = 1.f / fmaxf(sqrtf(sk), 1e-12f);
    row[tid] = s * rq * rk * temp[h];
  }
  __syncthreads();
  if (tid < 24) {
    float mx = -1e30f;
    for (int d = 0; d < 24; ++d) mx = fmaxf(mx, row[d]);
    float sum = 0.f;
    for (int d = 0; d < 24; ++d) sum += expf(row[d] - mx);
    atn[((size_t)b * NHEAD + h) * 576 + c * CH + tid] = expf(row[tid] - mx) / sum;
  }
}

// ---------------- PV -> pvt bf16 [b][s][192] (batched z) ----------------
__global__ __launch_bounds__(256) void attn_pv_bf16(const short* __restrict__ D,
                                                    const float* __restrict__ atn,
                                                    short* __restrict__ pvt) {
  int nb = blockIdx.x, h = blockIdx.y, b = blockIdx.z;
  __shared__ float aL[24][24];
  int tid = threadIdx.x;
  const float* ab = atn + ((size_t)b * NHEAD + h) * 576;
  for (int i = tid; i < 576; i += 256) aL[i / 24][i % 24] = ab[i];
  __syncthreads();
  int n = nb * 256 + tid;
  const short* vb = D + ((size_t)b * OC3 + 2 * CDIM + h * CH) * SSP + n;
  float vv[24];
#pragma unroll
  for (int d = 0; d < 24; ++d) vv[d] = bf2f(vb[(size_t)d * SSP]);
  short* ob = pvt + (size_t)b * SSP * CDIM + (size_t)n * CDIM + h * CH;
  bf16x8 o0, o1, o2;
#pragma unroll
  for (int cc = 0; cc < 24; ++cc) {
    float s = 0.f;
#pragma unroll
    for (int d = 0; d < 24; ++d) s += aL[cc][d] * vv[d];
    short bv = f2bf(s);
    if (cc < 8) o0[cc & 7] = bv; else if (cc < 16) o1[cc & 7] = bv; else o2[cc & 7] = bv;
  }
  *(bf16x8*)(ob) = o0;
  *(bf16x8*)(ob + 8) = o1;
  *(bf16x8*)(ob + 16) = o2;
}

// ---------------- fused MLP v3 + bf16 x1 residual + fast gelu + conflict-free LDS strides ----------------
// out[m][0..191] = gelu(y2[m][:] @ w1^T + b1) @ w2^T + b2 + x1w[m][:] ; 128 rows/block, 512 thr.
__global__ __launch_bounds__(512) void mlp_fused(const short* __restrict__ y2,
                                                 const short* __restrict__ w1,
                                                 const short* __restrict__ w2,
                                                 const float* __restrict__ b1,
                                                 const float* __restrict__ b2,
                                                 const short* __restrict__ x1w,
                                                 float* __restrict__ out) {
  __shared__ short y2s[128 * S1];   // 52224 B  (stride 204 sh = 102 w; 102%32=6)
  __shared__ short w1s[64 * S1];    // 26112 B
  __shared__ short w2s[192 * S2];   // 29184 B  (stride 76 sh = 38 w; 38%32=6)
  __shared__ short h1s[128 * S2];   // 19456 B  (total 126976 B)
  const int tid = threadIdx.x;
  const int m0 = blockIdx.x * 128;
  const int w = tid >> 6, lane = tid & 63;
  const int r16 = lane & 15, kg = lane >> 4;
  const int wm = w >> 1, wn = w & 1;

  const int u0 = tid, u1 = 512 + tid, u2 = 1024 + tid;
  const int s1r[3] = {u0 / 24, u1 / 24, u2 / 24};
  const int s1c[3] = {u0 % 24, u1 % 24, u2 % 24};
  const int s2r[3] = {u0 / 8, u1 / 8, u2 / 8};
  const int s2c[3] = {u0 % 8, u1 % 8, u2 % 8};

  // stage y2 tile once: 128 rows x 24 vec8 chunks = 3072 -> 6 per thread
#pragma unroll
  for (int it = 0; it < 6; ++it) {
    int u = it * 512 + tid;
    int row = u / 24, cx = u % 24;
    *(bf16x8*)(&y2s[row * S1 + cx * 8]) =
        *(const bf16x8*)(y2 + (size_t)(m0 + row) * CDIM + cx * 8);
  }
  // stage chunk-0 weights
#pragma unroll
  for (int it = 0; it < 3; ++it) {
    *(bf16x8*)(&w1s[s1r[it] * S1 + s1c[it] * 8]) =
        *(const bf16x8*)(w1 + (size_t)s1r[it] * CDIM + s1c[it] * 8);
    *(bf16x8*)(&w2s[s2r[it] * S2 + s2c[it] * 8]) =
        *(const bf16x8*)(w2 + (size_t)s2r[it] * HIDF + s2c[it] * 8);
  }
  __syncthreads();

  f32x4 bacc[2][6] = {};
  bf16x8 rw1[3], rw2[3];

  for (int hc = 0; hc < 12; ++hc) {
    if (hc < 11) {     // issue next chunk's weight loads early
#pragma unroll
      for (int it = 0; it < 3; ++it) {
        rw1[it] = *(const bf16x8*)(w1 + (size_t)((hc + 1) * 64 + s1r[it]) * CDIM + s1c[it] * 8);
        rw2[it] = *(const bf16x8*)(w2 + (size_t)s2r[it] * HIDF + (hc + 1) * 64 + s2c[it] * 8);
      }
    }
    // phase A (swapped): D[hid][m]
    f32x4 pacc[2][2] = {};
#pragma unroll
    for (int ks = 0; ks < 6; ++ks) {
      bf16x8 af[2], bg[2];
#pragma unroll
      for (int i = 0; i < 2; ++i)
        af[i] = *(bf16x8*)(&y2s[(wm * 32 + i * 16 + r16) * S1 + ks * 32 + kg * 8]);
#pragma unroll
      for (int j = 0; j < 2; ++j)
        bg[j] = *(bf16x8*)(&w1s[(wn * 32 + j * 16 + r16) * S1 + ks * 32 + kg * 8]);
#pragma unroll
      for (int i = 0; i < 2; ++i)
#pragma unroll
        for (int j = 0; j < 2; ++j)
          pacc[i][j] = __builtin_amdgcn_mfma_f32_16x16x32_bf16(bg[j], af[i], pacc[i][j], 0, 0, 0);
    }
    // bias + fast gelu (tanh form, hw exp) -> h1s packed 8B writes
#pragma unroll
    for (int i = 0; i < 2; ++i) {
      int mr = wm * 32 + i * 16 + r16;
#pragma unroll
      for (int j = 0; j < 2; ++j) {
        int hid0 = wn * 32 + j * 16 + kg * 4;
        bf16x4 pk;
#pragma unroll
        for (int t = 0; t < 4; ++t) {
          float v = pacc[i][j][t] + b1[hc * 64 + hid0 + t];
          float u = v * (0.7978845608f + 0.0356774081f * v * v);
          v = v / (1.f + __expf(-2.f * u));
          pk[t] = f2bf(v);
        }
        *(bf16x4*)(&h1s[mr * S2 + hid0]) = pk;
      }
    }
    __syncthreads();   // h1s visible

    // phase B: bacc += h1s @ w2s^T
#pragma unroll
    for (int ks = 0; ks < 2; ++ks) {
      bf16x8 a2[2];
#pragma unroll
      for (int i = 0; i < 2; ++i)
        a2[i] = *(bf16x8*)(&h1s[(wm * 32 + i * 16 + r16) * S2 + ks * 32 + kg * 8]);
#pragma unroll
      for (int j = 0; j < 6; ++j) {
        bf16x8 b2g = *(bf16x8*)(&w2s[(wn * 96 + j * 16 + r16) * S2 + ks * 32 + kg * 8]);
#pragma unroll
        for (int i = 0; i < 2; ++i)
          bacc[i][j] = __builtin_amdgcn_mfma_f32_16x16x32_bf16(a2[i], b2g, bacc[i][j], 0, 0, 0);
      }
    }
    __syncthreads();   // all reads done

    // write prefetched regs -> LDS for next chunk
    if (hc < 11) {
#pragma unroll
      for (int it = 0; it < 3; ++it) {
        *(bf16x8*)(&w1s[s1r[it] * S1 + s1c[it] * 8]) = rw1[it];
        *(bf16x8*)(&w2s[s2r[it] * S2 + s2c[it] * 8]) = rw2[it];
      }
      __syncthreads();
    }
  }

  // epilogue: out = bacc + b2 + x1(bf16) — sole writer of d_out
#pragma unroll
  for (int i = 0; i < 2; ++i)
#pragma unroll
    for (int j = 0; j < 6; ++j)
#pragma unroll
      for (int t = 0; t < 4; ++t) {
        int m = m0 + wm * 32 + i * 16 + kg * 4 + t;
        int n = wn * 96 + j * 16 + r16;
        size_t idx = (size_t)m * CDIM + n;
        out[idx] = bacc[i][j][t] + b2[n] + bf2f(x1w[idx]);
      }
}

extern "C" void kernel_launch(void* const* d_in, const int* in_sizes, int n_in,
                              void* d_out, int out_size, void* d_ws, size_t ws_size,
                              hipStream_t stream) {
  const float* x      = (const float*)d_in[0];
  const float* ln1_w  = (const float*)d_in[1];
  const float* ln1_b  = (const float*)d_in[2];
  const float* temp   = (const float*)d_in[3];
  const float* qkv_w  = (const float*)d_in[4];
  const float* dw_w   = (const float*)d_in[5];
  const float* proj_w = (const float*)d_in[6];
  const float* ln2_w  = (const float*)d_in[7];
  const float* ln2_b  = (const float*)d_in[8];
  const float* fc1_w  = (const float*)d_in[9];
  const float* fc1_b  = (const float*)d_in[10];
  const float* fc2_w  = (const float*)d_in[11];
  const float* fc2_b  = (const float*)d_in[12];
  float* out = (float*)d_out;

  char* base = (char*)d_ws;
  short* wq  = (short*)base;
  short* wp  = wq + 110592;
  short* w1  = wp + 36864;
  short* w2  = w1 + 147456;
  float* pdot= (float*)(base + 890880);
  float* qss = (float*)(base + 2660352);
  float* kss = (float*)(base + 2734080);
  float* atn = (float*)(base + 2807808);
  short* Dv  = (short*)(base + 4194304);         // [4][576][SSP] bf16 (226.5 MB)
  short* y1t = Dv;                               // [4][SSP][192] overlay (dead before Dv)
  short* x1w = Dv;                               // [4][192][SSP] bf16 overlay (Dv dead after pv)
  short* T   = (short*)(base + 230686720);       // [4][576][SSP] bf16
  short* pvt = T;                                // overlay (T dead after dwconv)
  short* y2  = (short*)(base + 457179136);       // [4][192][SSP] bf16

  // weights -> bf16 (one launch)
  cvt_all<<<dim3(1728), 256, 0, stream>>>(qkv_w, proj_w, fc1_w, fc2_w, wq);

  // 1. LN1 -> y1t bf16 [b][s][192] (single-read)
  ln_bf16<true, false><<<dim3(SSP / 64, NB), 256, 0, stream>>>(x, ln1_w, ln1_b, y1t);
  // 2. qkv GEMM (M=576,N=SSP,K=192, z=4) -> T bf16
  mfma_gemmx<false, true><<<dim3(SSP / 256, OC3 / 64, NB), 256, 0, stream>>>(
      wq, y1t, nullptr, T, OC3, SSP, CDIM, (long long)SSP * CDIM, (long long)OC3 * SSP);
  // 3. depthwise 3x3 tiled -> Dv bf16
  dwconv_tile<<<dim3(NB * OC3 * 8), 256, 0, stream>>>(T, dw_w, Dv);
  // 4. scores: partial dots + sumsq, then reduce+norm+softmax
  scores_stage1<<<dim3(SCCH, NHEAD, NB), 256, 0, stream>>>(Dv, pdot, qss, kss);
  scores_reduce<<<dim3(CH, NHEAD, NB), 64, 0, stream>>>(pdot, qss, kss, temp, atn);
  // 5. PV -> pvt bf16 [b][s][192]
  attn_pv_bf16<<<dim3(SSP / 256, NHEAD, NB), 256, 0, stream>>>(Dv, atn, pvt);
  // 6. x1 = proj @ pv + x -> x1w (bf16, overlays dead Dv)
  mfma_gemmx<true, true><<<dim3(SSP / 256, CDIM / 64, NB), 256, 0, stream>>>(
      wp, pvt, x, x1w, CDIM, SSP, CDIM, (long long)SSP * CDIM, (long long)CDIM * SSP);
  // 7. LN2 -> y2 bf16 [b][c][s] (bf16 input, single-read)
  ln_bf16<false, true><<<dim3(SSP / 64, NB), 256, 0, stream>>>(x1w, ln2_w, ln2_b, y2);
  // 8. fused MLP v3 (fast gelu, padded strides) + bf16 residual
  mlp_fused<<<dim3(196608 / 128), 512, 0, stream>>>(y2, w1, w2, fc1_b, fc2_b, x1w, out);
}